// Round 6
// baseline (603.681 us; speedup 1.0000x reference)
//
#include <hip/hip_runtime.h>
#include <hip/hip_bf16.h>
#include <cstdint>
#include <cstddef>

// Problem constants
#define B_ 64
#define S_ 4096
#define D_ 256
#define TPB 512                  // 8 waves
#define NBLK 256                 // 1 block per CU; 256 blocks * 1024 rows = 262144
#define ROWS_PER_BLOCK 1024
#define ROWS_PER_WAVE 128        // 8 t-iters of 16 rows
#define BLKS_PER_BATCH 4         // 4096 rows/batch / 1024 rows/block

typedef __attribute__((ext_vector_type(8))) short short8;
typedef __attribute__((ext_vector_type(4))) float f32x4;
typedef __attribute__((ext_vector_type(4))) float f4;

__device__ __forceinline__ short f2bf(float f) {
  union { float f; uint32_t u; } v; v.f = f;
  uint32_t r = v.u + 0x7FFFu + ((v.u >> 16) & 1u);   // RNE
  return (short)(r >> 16);
}

__device__ __forceinline__ float fast_tanh(float z) {
  // tanh(z) = 1 - 2/(e^{2z}+1); overflow-safe
  return 1.0f - 2.0f * __builtin_amdgcn_rcpf(__expf(2.0f * z) + 1.0f);
}

__device__ __forceinline__ void gload_lds16(const short* g, short* l) {
  __builtin_amdgcn_global_load_lds(
      (const __attribute__((address_space(1))) int*)(g),
      (__attribute__((address_space(3))) int*)(l), 16, 0, 0);
}

// Kernel 0: Wt image = bf16(W^T) in the EXACT swizzled LDS byte layout:
// element (n,k) at short index n*256 + (((k>>3) ^ (n&7))<<3) + (k&7).
__global__ void k_pack(const float* __restrict__ W, short* __restrict__ wt) {
  __shared__ float tile[64][65];
  int t = blockIdx.x, ti = t >> 2, tj = t & 3;
  int tid = threadIdx.x;
#pragma unroll
  for (int i = 0; i < 16; ++i) {
    int idx = i * 256 + tid;
    int r = idx >> 6, c = idx & 63;                 // r: k-local, c: n-local
    tile[c][r] = W[(ti * 64 + r) * 256 + tj * 64 + c];
  }
  __syncthreads();
#pragma unroll
  for (int i = 0; i < 16; ++i) {
    int idx = i * 256 + tid;
    int r = idx >> 6, c = idx & 63;                 // r: n-local, c: k-local
    int n = tj * 64 + r, k = ti * 64 + c;
    int si = n * 256 + ((((k >> 3) ^ (n & 7)) << 3) | (k & 7));
    wt[si] = f2bf(tile[r][c]);
  }
}

// Consume one prefetch slot (4 named f4 regs) -> 2 A-frags -> refill slot
// with chunk H -> 32 MFMAs. All indices compile-time static; NO local arrays
// accessed through pointers (scratch avoidance).
#define STEP(S0, S1, S2, S3, QQ, HH)                                          \
  {                                                                           \
    short8 a0, a1;                                                            \
    a0[0]=f2bf(S0[0]); a0[1]=f2bf(S0[1]); a0[2]=f2bf(S0[2]); a0[3]=f2bf(S0[3]); \
    a0[4]=f2bf(S1[0]); a0[5]=f2bf(S1[1]); a0[6]=f2bf(S1[2]); a0[7]=f2bf(S1[3]); \
    a1[0]=f2bf(S2[0]); a1[1]=f2bf(S2[1]); a1[2]=f2bf(S2[2]); a1[3]=f2bf(S2[3]); \
    a1[4]=f2bf(S3[0]); a1[5]=f2bf(S3[1]); a1[6]=f2bf(S3[2]); a1[7]=f2bf(S3[3]); \
    int h = (HH);                                                             \
    if (h < 32) {                                                             \
      const float* p = xw + (h >> 2) * (16 * D_) + (h & 3) * 64;              \
      S0 = *(const f4*)(p);                                                   \
      S1 = *(const f4*)(p + 4);                                               \
      S2 = *(const f4*)(p + 32);                                              \
      S3 = *(const f4*)(p + 36);                                              \
    }                                                                         \
    const int sw0 = (((2 * (QQ)) * 4 + gr) ^ (cl & 7)) << 3;                  \
    const int sw1 = (((2 * (QQ) + 1) * 4 + gr) ^ (cl & 7)) << 3;              \
    _Pragma("unroll")                                                         \
    for (int nf = 0; nf < 16; ++nf) {                                         \
      short8 b0 = *(const short8*)&lsB[(nf * 16 + cl) * 256 + sw0];           \
      acc[nf] = __builtin_amdgcn_mfma_f32_16x16x32_bf16(a0, b0, acc[nf], 0, 0, 0); \
      short8 b1 = *(const short8*)&lsB[(nf * 16 + cl) * 256 + sw1];           \
      acc[nf] = __builtin_amdgcn_mfma_f32_16x16x32_bf16(a1, b1, acc[nf], 0, 0, 0); \
    }                                                                         \
  }

// Kernel 1: barrier-free streaming GEMM+tanh+dot+online-softmax+context.
// B resident in LDS (preloaded once); each wave owns 128 private rows.
__global__ __launch_bounds__(TPB, 2)
void k_scores(const float* __restrict__ x, const short* __restrict__ wt,
              const float* __restrict__ bias, const float* __restrict__ u,
              float* __restrict__ ws_scores, float* __restrict__ ws_m,
              float* __restrict__ ws_l, float* __restrict__ ws_c) {
  __shared__ __align__(16) short lsB[D_ * D_];   // 128 KB swizzled Wt; reused as ctx at end
  __shared__ __align__(8) float bu[D_ * 2];      // (bias, u) pairs
  __shared__ float ml[8 * 2];

  const int tid  = threadIdx.x;
  const int lane = tid & 63;
  const int wv   = tid >> 6;        // 0..7
  const int cl   = lane & 15;
  const int gr   = lane >> 4;       // 0..3
  const int bid  = blockIdx.x;

  // ---- preload B (128 KB) + (bias,u) into LDS, one barrier
#pragma unroll
  for (int i = 0; i < 16; ++i) {
    int idx = i * TPB + tid;
    gload_lds16(wt + idx * 8, &lsB[idx * 8]);
  }
  if (tid < D_) {
    bu[tid * 2]     = bias[tid];
    bu[tid * 2 + 1] = u[tid];
  }
  __syncthreads();

  const size_t rowbase0 = (size_t)bid * ROWS_PER_BLOCK + wv * ROWS_PER_WAVE;
  const float* xw = x + (rowbase0 + cl) * D_ + gr * 8;   // A-load base for this lane

  // rolling A prefetch, depth 2, NAMED slots (no local arrays -> no scratch)
  f4 sA0, sA1, sA2, sA3, sB0, sB1, sB2, sB3;
  {
    const float* p0 = xw;              // chunk 0
    sA0 = *(const f4*)(p0);      sA1 = *(const f4*)(p0 + 4);
    sA2 = *(const f4*)(p0 + 32); sA3 = *(const f4*)(p0 + 36);
    const float* p1 = xw + 64;         // chunk 1
    sB0 = *(const f4*)(p1);      sB1 = *(const f4*)(p1 + 4);
    sB2 = *(const f4*)(p1 + 32); sB3 = *(const f4*)(p1 + 36);
  }

  float mrun = -3.4e38f, lrun = 0.f;
  f4 ctxv = (f4){0.f, 0.f, 0.f, 0.f};

  for (int t = 0; t < 8; ++t) {
    f32x4 acc[16];
#pragma unroll
    for (int nf = 0; nf < 16; ++nf) acc[nf] = (f32x4){0.f, 0.f, 0.f, 0.f};

    STEP(sA0, sA1, sA2, sA3, 0, t * 4 + 2)
    STEP(sB0, sB1, sB2, sB3, 1, t * 4 + 3)
    STEP(sA0, sA1, sA2, sA3, 2, t * 4 + 4)
    STEP(sB0, sB1, sB2, sB3, 3, t * 4 + 5)

    // ---- epilogue: scores for 16 rows (row = gr*4+j), online softmax, ctx
    float sj0 = 0.f, sj1 = 0.f, sj2 = 0.f, sj3 = 0.f;
#pragma unroll
    for (int nf = 0; nf < 16; ++nf) {
      float bb = bu[(nf * 16 + cl) * 2];
      float uu = bu[(nf * 16 + cl) * 2 + 1];
      sj0 += fast_tanh(acc[nf][0] + bb) * uu;
      sj1 += fast_tanh(acc[nf][1] + bb) * uu;
      sj2 += fast_tanh(acc[nf][2] + bb) * uu;
      sj3 += fast_tanh(acc[nf][3] + bb) * uu;
    }
#pragma unroll
    for (int m = 1; m < 16; m <<= 1) {
      sj0 += __shfl_xor(sj0, m); sj1 += __shfl_xor(sj1, m);
      sj2 += __shfl_xor(sj2, m); sj3 += __shfl_xor(sj3, m);
    }
    const int rowb = bid * ROWS_PER_BLOCK + wv * ROWS_PER_WAVE + t * 16;
    if (cl == 0) {
      ws_scores[rowb + gr * 4 + 0] = sj0;
      ws_scores[rowb + gr * 4 + 1] = sj1;
      ws_scores[rowb + gr * 4 + 2] = sj2;
      ws_scores[rowb + gr * 4 + 3] = sj3;
    }
    float tmax = fmaxf(fmaxf(sj0, sj1), fmaxf(sj2, sj3));
    tmax = fmaxf(tmax, __shfl_xor(tmax, 16));
    tmax = fmaxf(tmax, __shfl_xor(tmax, 32));
    float mnew = fmaxf(mrun, tmax);
    float sc = __expf(mrun - mnew);
    float e0 = __expf(sj0 - mnew), e1 = __expf(sj1 - mnew);
    float e2 = __expf(sj2 - mnew), e3 = __expf(sj3 - mnew);
    float se = e0 + e1 + e2 + e3;
    se += __shfl_xor(se, 16); se += __shfl_xor(se, 32);
    lrun = lrun * sc + se;
    mrun = mnew;
    ctxv *= sc;
    // context accumulate: re-read the (L2-hot) 16-row tile; lane owns d = lane*4..+3
    const float* xc = x + (size_t)rowb * D_ + lane * 4;
#pragma unroll
    for (int s = 0; s < 16; ++s) {
      f4 xv = *(const f4*)(xc + (size_t)s * D_);
      uint32_t eu;
      if ((s & 3) == 0)      eu = __float_as_uint(e0);
      else if ((s & 3) == 1) eu = __float_as_uint(e1);
      else if ((s & 3) == 2) eu = __float_as_uint(e2);
      else                   eu = __float_as_uint(e3);
      float es = __uint_as_float(__builtin_amdgcn_readlane(eu, (s >> 2) << 4));
      ctxv += es * xv;
    }
  }

  // ---- block combine (reuse lsB as ctx scratch)
  __syncthreads();                    // all waves done reading lsB
  ((f4*)lsB)[wv * 64 + lane] = ctxv;  // [wv][256] f32
  if (lane == 0) { ml[wv * 2] = mrun; ml[wv * 2 + 1] = lrun; }
  __syncthreads();
  if (tid < D_) {
    float M = ml[0];
#pragma unroll
    for (int w = 1; w < 8; ++w) M = fmaxf(M, ml[w * 2]);
    float L = 0.f, cd = 0.f;
#pragma unroll
    for (int w = 0; w < 8; ++w) {
      float ex = __expf(ml[w * 2] - M);
      L += ml[w * 2 + 1] * ex;
      cd += ((const float*)lsB)[w * 256 + tid] * ex;
    }
    ws_c[bid * D_ + tid] = cd;
    if (tid == 0) { ws_m[bid] = M; ws_l[bid] = L; }
  }
}

// Kernel 2: per-batch combine of 4 block partials -> context out + (M, L)
__global__ void k_combine(const float* __restrict__ ws_m, const float* __restrict__ ws_l,
                          const float* __restrict__ ws_c, float* __restrict__ out_ctx,
                          float* __restrict__ ws_M, float* __restrict__ ws_L) {
  int b = blockIdx.x, d = threadIdx.x;
  float M = -3.4e38f;
#pragma unroll
  for (int i = 0; i < BLKS_PER_BATCH; ++i) M = fmaxf(M, ws_m[b * BLKS_PER_BATCH + i]);
  float L = 0.f, c = 0.f;
#pragma unroll
  for (int i = 0; i < BLKS_PER_BATCH; ++i) {
    float f = __expf(ws_m[b * BLKS_PER_BATCH + i] - M);
    L += ws_l[b * BLKS_PER_BATCH + i] * f;
    c += ws_c[(size_t)(b * BLKS_PER_BATCH + i) * D_ + d] * f;
  }
  out_ctx[b * D_ + d] = c / L;
  if (d == 0) { ws_M[b] = M; ws_L[b] = L; }
}

// Kernel 3: weights[b,s] = exp(score - M_b) / L_b
__global__ void k_weights(const float* __restrict__ ws_scores, const float* __restrict__ ws_M,
                          const float* __restrict__ ws_L, float* __restrict__ out_w) {
  int idx = blockIdx.x * 256 + threadIdx.x;
  int b = idx >> 12;
  out_w[idx] = __expf(ws_scores[idx] - ws_M[b]) / ws_L[b];
}

extern "C" void kernel_launch(void* const* d_in, const int* in_sizes, int n_in,
                              void* d_out, int out_size, void* d_ws, size_t ws_size,
                              hipStream_t stream) {
  (void)in_sizes; (void)n_in; (void)out_size; (void)ws_size;
  const float* x    = (const float*)d_in[0];
  const float* W    = (const float*)d_in[1];
  const float* bias = (const float*)d_in[2];
  const float* u    = (const float*)d_in[3];
  float* out_ctx = (float*)d_out;                 // [64,256]
  float* out_w   = (float*)d_out + B_ * D_;       // [64,4096]

  char* ws = (char*)d_ws;
  short* wt        = (short*)(ws + 0);            // 131072 B (swizzled LDS image)
  float* ws_scores = (float*)(ws + 131072);       // 1048576 B
  float* ws_m      = (float*)(ws + 1179648);      // 1024 B (256 blocks)
  float* ws_l      = (float*)(ws + 1180672);      // 1024 B
  float* ws_c      = (float*)(ws + 1181696);      // 262144 B (256 x 256)
  float* ws_M      = (float*)(ws + 1443840);      // 256 B
  float* ws_L      = (float*)(ws + 1444096);      // 256 B

  hipLaunchKernelGGL(k_pack, dim3(16), dim3(256), 0, stream, W, wt);
  hipLaunchKernelGGL(k_scores, dim3(NBLK), dim3(TPB), 0, stream,
                     x, wt, bias, u, ws_scores, ws_m, ws_l, ws_c);
  hipLaunchKernelGGL(k_combine, dim3(B_), dim3(256), 0, stream,
                     ws_m, ws_l, ws_c, out_ctx, ws_M, ws_L);
  hipLaunchKernelGGL(k_weights, dim3(B_ * S_ / 256), dim3(256), 0, stream,
                     ws_scores, ws_M, ws_L, out_w);
}

// Round 7
// 140.076 us; speedup vs baseline: 4.3097x; 4.3097x over previous
//
#include <hip/hip_runtime.h>
#include <hip/hip_bf16.h>
#include <cstdint>
#include <cstddef>

// Problem constants
#define B_ 64
#define S_ 4096
#define D_ 256
#define BM 128                  // rows per block (4 waves x 32 rows)
#define BK 64                   // k-chunk
#define NBLK (B_ * S_ / BM)     // 2048
#define BLKS_PER_B (S_ / BM)    // 32

typedef __attribute__((ext_vector_type(8))) short short8;
typedef __attribute__((ext_vector_type(4))) float f32x4;
typedef __attribute__((ext_vector_type(4))) float f4;

__device__ __forceinline__ short f2bf(float f) {
  union { float f; uint32_t u; } v; v.f = f;
  uint32_t r = v.u + 0x7FFFu + ((v.u >> 16) & 1u);   // RNE
  return (short)(r >> 16);
}

__device__ __forceinline__ float fast_tanh(float z) {
  // tanh(z) = 1 - 2/(e^{2z}+1); overflow-safe
  return 1.0f - 2.0f / (__expf(2.0f * z) + 1.0f);
}

__device__ __forceinline__ void gload_lds16(const short* g, short* l) {
  __builtin_amdgcn_global_load_lds(
      (const __attribute__((address_space(1))) int*)(g),
      (__attribute__((address_space(3))) int*)(l), 16, 0, 0);
}

// Kernel 0: Wt[n][k] = bf16(W[k][n]) via LDS tile transpose. grid 16, 256 thr.
__global__ void k_pack(const float* __restrict__ W, short* __restrict__ wt) {
  __shared__ float tile[64][65];
  int t = blockIdx.x, ti = t >> 2, tj = t & 3;
  int tid = threadIdx.x;
#pragma unroll
  for (int i = 0; i < 16; ++i) {
    int idx = i * 256 + tid;
    int r = idx >> 6, c = idx & 63;                 // r: k-local, c: n-local
    tile[c][r] = W[(ti * 64 + r) * 256 + tj * 64 + c];
  }
  __syncthreads();
#pragma unroll
  for (int i = 0; i < 16; ++i) {
    int idx = i * 256 + tid;
    int r = idx >> 6, c = idx & 63;                 // r: n-local, c: k-local
    wt[(tj * 64 + r) * 256 + ti * 64 + c] = f2bf(tile[r][c]);
  }
}

// Kernel 1: fused GEMM(x@W)+tanh+dot(u) -> scores; per-block softmax partials
// (m, l) and context partial. grid NBLK, 256 thr (4 waves, 32 rows each).
// A direct global->reg; B async-staged per kc into LDS (pre-swizzled source).
// Each B ds_read feeds TWO MFMAs (rows cl and cl+16) -> half the LDS-pipe cost.
__global__ __launch_bounds__(256, 2)
void k_scores(const float* __restrict__ x, const short* __restrict__ wt,
              const float* __restrict__ bias, const float* __restrict__ u,
              float* __restrict__ ws_scores, float* __restrict__ ws_m,
              float* __restrict__ ws_l, float* __restrict__ ws_c) {
  __shared__ __align__(16) short lsB[D_ * BK];   // [256 n][64 k] shorts, 32 KB
  __shared__ __align__(8) float bu[D_ * 2];      // (bias, u) pairs
  __shared__ float score_lds[BM];
  __shared__ float e_lds[BM];
  __shared__ float red_lds[1];

  const int tid  = threadIdx.x;
  const int bid  = blockIdx.x;
  const int m0   = bid * BM;
  const int lane = tid & 63;
  const int wv   = tid >> 6;       // 0..3 : 32-row group
  const int cl   = lane & 15;
  const int gr   = lane >> 4;      // 0..3

  f32x4 acc0[16], acc1[16];
#pragma unroll
  for (int j = 0; j < 16; ++j) {
    acc0[j] = (f32x4){0.f, 0.f, 0.f, 0.f};
    acc1[j] = (f32x4){0.f, 0.f, 0.f, 0.f};
  }

  // stage kc=0 (LDS linear dest, pre-swizzled global source column)
#pragma unroll
  for (int i = 0; i < 8; ++i) {
    int idx = i * 256 + tid;
    int n = idx >> 3, c8 = idx & 7;
    gload_lds16(wt + n * 256 + ((c8 ^ (n & 7)) << 3), &lsB[idx * 8]);
  }
  if (tid < D_) {
    bu[tid * 2]     = bias[tid];
    bu[tid * 2 + 1] = u[tid];
  }

  const float* xrow0 = x + (size_t)(m0 + wv * 32 + cl) * D_;        // rows cl
  const float* xrow1 = xrow0 + 16 * D_;                             // rows cl+16
  const int rbase = cl * 64;                                        // LDS row stride 64 shorts
  const int sw0 = ((0 + gr) ^ (cl & 7)) << 3;                       // ks=0 quad swizzle
  const int sw1 = ((4 + gr) ^ (cl & 7)) << 3;                       // ks=1

  for (int kc = 0; kc < 4; ++kc) {
    // A fragments direct from global (fp32), issued before the stage barrier
    f4 a00 = *(const f4*)(xrow0 + kc * 64 + gr * 8);
    f4 a01 = *(const f4*)(xrow0 + kc * 64 + gr * 8 + 4);
    f4 a02 = *(const f4*)(xrow0 + kc * 64 + 32 + gr * 8);
    f4 a03 = *(const f4*)(xrow0 + kc * 64 + 32 + gr * 8 + 4);
    f4 a10 = *(const f4*)(xrow1 + kc * 64 + gr * 8);
    f4 a11 = *(const f4*)(xrow1 + kc * 64 + gr * 8 + 4);
    f4 a12 = *(const f4*)(xrow1 + kc * 64 + 32 + gr * 8);
    f4 a13 = *(const f4*)(xrow1 + kc * 64 + 32 + gr * 8 + 4);
    __syncthreads();   // B(kc) staged (vmcnt drain also covers A loads)

    short8 f0k0, f0k1, f1k0, f1k1;
    f0k0[0]=f2bf(a00[0]); f0k0[1]=f2bf(a00[1]); f0k0[2]=f2bf(a00[2]); f0k0[3]=f2bf(a00[3]);
    f0k0[4]=f2bf(a01[0]); f0k0[5]=f2bf(a01[1]); f0k0[6]=f2bf(a01[2]); f0k0[7]=f2bf(a01[3]);
    f0k1[0]=f2bf(a02[0]); f0k1[1]=f2bf(a02[1]); f0k1[2]=f2bf(a02[2]); f0k1[3]=f2bf(a02[3]);
    f0k1[4]=f2bf(a03[0]); f0k1[5]=f2bf(a03[1]); f0k1[6]=f2bf(a03[2]); f0k1[7]=f2bf(a03[3]);
    f1k0[0]=f2bf(a10[0]); f1k0[1]=f2bf(a10[1]); f1k0[2]=f2bf(a10[2]); f1k0[3]=f2bf(a10[3]);
    f1k0[4]=f2bf(a11[0]); f1k0[5]=f2bf(a11[1]); f1k0[6]=f2bf(a11[2]); f1k0[7]=f2bf(a11[3]);
    f1k1[0]=f2bf(a12[0]); f1k1[1]=f2bf(a12[1]); f1k1[2]=f2bf(a12[2]); f1k1[3]=f2bf(a12[3]);
    f1k1[4]=f2bf(a13[0]); f1k1[5]=f2bf(a13[1]); f1k1[6]=f2bf(a13[2]); f1k1[7]=f2bf(a13[3]);

#pragma unroll
    for (int nf = 0; nf < 16; ++nf) {
      short8 b0 = *(const short8*)&lsB[nf * 1024 + rbase + sw0];
      acc0[nf] = __builtin_amdgcn_mfma_f32_16x16x32_bf16(f0k0, b0, acc0[nf], 0, 0, 0);
      acc1[nf] = __builtin_amdgcn_mfma_f32_16x16x32_bf16(f1k0, b0, acc1[nf], 0, 0, 0);
      short8 b1 = *(const short8*)&lsB[nf * 1024 + rbase + sw1];
      acc0[nf] = __builtin_amdgcn_mfma_f32_16x16x32_bf16(f0k1, b1, acc0[nf], 0, 0, 0);
      acc1[nf] = __builtin_amdgcn_mfma_f32_16x16x32_bf16(f1k1, b1, acc1[nf], 0, 0, 0);
    }
    __syncthreads();   // all waves done reading lsB
    if (kc < 3) {
#pragma unroll
      for (int i = 0; i < 8; ++i) {
        int idx = i * 256 + tid;
        int n = idx >> 3, c8 = idx & 7;
        gload_lds16(wt + n * 256 + (kc + 1) * 64 + ((c8 ^ (n & 7)) << 3), &lsB[idx * 8]);
      }
    }
  }

  // Epilogue: score[row] = sum_n tanh(acc[row][n] + b[n]) * u[n]
#pragma unroll
  for (int mi = 0; mi < 2; ++mi) {
    float p0 = 0.f, p1 = 0.f, p2 = 0.f, p3 = 0.f;
#pragma unroll
    for (int nf = 0; nf < 16; ++nf) {
      float bb = bu[(nf * 16 + cl) * 2];
      float uu = bu[(nf * 16 + cl) * 2 + 1];
      f32x4 av = (mi == 0) ? acc0[nf] : acc1[nf];
      p0 += fast_tanh(av[0] + bb) * uu;
      p1 += fast_tanh(av[1] + bb) * uu;
      p2 += fast_tanh(av[2] + bb) * uu;
      p3 += fast_tanh(av[3] + bb) * uu;
    }
#pragma unroll
    for (int m = 1; m < 16; m <<= 1) {
      p0 += __shfl_xor(p0, m);
      p1 += __shfl_xor(p1, m);
      p2 += __shfl_xor(p2, m);
      p3 += __shfl_xor(p3, m);
    }
    if (cl == 0) {
      int r = wv * 32 + mi * 16 + gr * 4;
      score_lds[r + 0] = p0;
      score_lds[r + 1] = p1;
      score_lds[r + 2] = p2;
      score_lds[r + 3] = p3;
      ws_scores[m0 + r + 0] = p0;
      ws_scores[m0 + r + 1] = p1;
      ws_scores[m0 + r + 2] = p2;
      ws_scores[m0 + r + 3] = p3;
    }
  }
  __syncthreads();
  // block max over the 128 scores
  if (tid < 64) {
    float v = fmaxf(score_lds[tid], score_lds[tid + 64]);
#pragma unroll
    for (int m = 32; m >= 1; m >>= 1) v = fmaxf(v, __shfl_xor(v, m));
    if (tid == 0) red_lds[0] = v;
  }
  __syncthreads();
  float mb = red_lds[0];
  if (tid < BM) e_lds[tid] = __expf(score_lds[tid] - mb);
  __syncthreads();
  if (tid < 64) {
    float v = e_lds[tid] + e_lds[tid + 64];
#pragma unroll
    for (int m = 32; m >= 1; m >>= 1) v += __shfl_xor(v, m);
    if (tid == 0) { ws_m[bid] = mb; ws_l[bid] = v; }
  }
  // context partial: thread owns column d = tid; x tile is L1/L2-hot
  float cacc = 0.f;
  const float* xp = x + (size_t)m0 * D_ + tid;
#pragma unroll 4
  for (int s = 0; s < BM; ++s) cacc += e_lds[s] * xp[(size_t)s * D_];
  ws_c[bid * D_ + tid] = cacc;
}

// Kernel 2: per-batch combine of 32 block partials -> context out + (M, L)
__global__ void k_combine(const float* __restrict__ ws_m, const float* __restrict__ ws_l,
                          const float* __restrict__ ws_c, float* __restrict__ out_ctx,
                          float* __restrict__ ws_M, float* __restrict__ ws_L) {
  int b = blockIdx.x, d = threadIdx.x;
  float M = -3.4e38f;
#pragma unroll
  for (int i = 0; i < BLKS_PER_B; ++i) M = fmaxf(M, ws_m[b * BLKS_PER_B + i]);
  float L = 0.f, c = 0.f;
#pragma unroll 4
  for (int i = 0; i < BLKS_PER_B; ++i) {
    float f = __expf(ws_m[b * BLKS_PER_B + i] - M);
    L += ws_l[b * BLKS_PER_B + i] * f;
    c += ws_c[(size_t)(b * BLKS_PER_B + i) * D_ + d] * f;
  }
  out_ctx[b * D_ + d] = c / L;
  if (d == 0) { ws_M[b] = M; ws_L[b] = L; }
}

// Kernel 3: weights[b,s] = exp(score - M_b) / L_b
__global__ void k_weights(const float* __restrict__ ws_scores, const float* __restrict__ ws_M,
                          const float* __restrict__ ws_L, float* __restrict__ out_w) {
  int idx = blockIdx.x * 256 + threadIdx.x;
  int b = idx >> 12;
  out_w[idx] = __expf(ws_scores[idx] - ws_M[b]) / ws_L[b];
}

extern "C" void kernel_launch(void* const* d_in, const int* in_sizes, int n_in,
                              void* d_out, int out_size, void* d_ws, size_t ws_size,
                              hipStream_t stream) {
  (void)in_sizes; (void)n_in; (void)out_size; (void)ws_size;
  const float* x    = (const float*)d_in[0];
  const float* W    = (const float*)d_in[1];
  const float* bias = (const float*)d_in[2];
  const float* u    = (const float*)d_in[3];
  float* out_ctx = (float*)d_out;                 // [64,256]
  float* out_w   = (float*)d_out + B_ * D_;       // [64,4096]

  char* ws = (char*)d_ws;
  short* wt        = (short*)(ws + 0);            // 131072 B
  float* ws_scores = (float*)(ws + 131072);       // 1048576 B
  float* ws_m      = (float*)(ws + 1179648);      // 8192 B
  float* ws_l      = (float*)(ws + 1187840);      // 8192 B
  float* ws_c      = (float*)(ws + 1196032);      // 2097152 B
  float* ws_M      = (float*)(ws + 3293184);      // 256 B
  float* ws_L      = (float*)(ws + 3293440);      // 256 B

  hipLaunchKernelGGL(k_pack, dim3(16), dim3(256), 0, stream, W, wt);
  hipLaunchKernelGGL(k_scores, dim3(NBLK), dim3(256), 0, stream,
                     x, wt, bias, u, ws_scores, ws_m, ws_l, ws_c);
  hipLaunchKernelGGL(k_combine, dim3(B_), dim3(256), 0, stream,
                     ws_m, ws_l, ws_c, out_ctx, ws_M, ws_L);
  hipLaunchKernelGGL(k_weights, dim3(B_ * S_ / 256), dim3(256), 0, stream,
                     ws_scores, ws_M, ws_L, out_w);
}

// Round 8
// 115.917 us; speedup vs baseline: 5.2079x; 1.2084x over previous
//
#include <hip/hip_runtime.h>
#include <hip/hip_bf16.h>
#include <cstdint>
#include <cstddef>

// Problem constants
#define B_ 64
#define S_ 4096
#define D_ 256
#define BM 64                   // rows per block (4 waves x 16 rows)
#define BK 32                   // k-step
#define NBLK (B_ * S_ / BM)     // 4096
#define BLKS_PER_B (S_ / BM)    // 64

typedef __attribute__((ext_vector_type(8))) short short8;
typedef __attribute__((ext_vector_type(4))) float f32x4;
typedef __attribute__((ext_vector_type(4))) float f4;

__device__ __forceinline__ short f2bf(float f) {
  union { float f; uint32_t u; } v; v.f = f;
  uint32_t r = v.u + 0x7FFFu + ((v.u >> 16) & 1u);   // RNE
  return (short)(r >> 16);
}

__device__ __forceinline__ float fast_tanh(float z) {
  // tanh(z) = 1 - 2/(e^{2z}+1); overflow-safe; rcp approx OK for 3.7e-3 budget
  return 1.0f - 2.0f * __builtin_amdgcn_rcpf(__expf(2.0f * z) + 1.0f);
}

__device__ __forceinline__ void gload_lds16(const short* g, short* l) {
  __builtin_amdgcn_global_load_lds(
      (const __attribute__((address_space(1))) int*)(g),
      (__attribute__((address_space(3))) int*)(l), 16, 0, 0);
}

// Kernel 0: Wt[n][k] = bf16(W[k][n]) via LDS tile transpose. grid 16, 1024 thr.
__global__ void k_pack(const float* __restrict__ W, short* __restrict__ wt) {
  __shared__ float tile[64][65];
  int t = blockIdx.x, ti = t >> 2, tj = t & 3;
  int tid = threadIdx.x;
#pragma unroll
  for (int i = 0; i < 4; ++i) {
    int idx = i * 1024 + tid;
    int r = idx >> 6, c = idx & 63;                 // r: k-local, c: n-local
    tile[c][r] = W[(ti * 64 + r) * 256 + tj * 64 + c];
  }
  __syncthreads();
#pragma unroll
  for (int i = 0; i < 4; ++i) {
    int idx = i * 1024 + tid;
    int r = idx >> 6, c = idx & 63;                 // r: n-local, c: k-local
    wt[(tj * 64 + r) * 256 + ti * 64 + c] = f2bf(tile[r][c]);
  }
}

// ---- k_scores helper macros -------------------------------------------------
#define WAITV(N) asm volatile("s_waitcnt vmcnt(" #N ")" ::: "memory")
#define FENCE()  asm volatile("" ::: "memory")

// Stage B k-step KC into lsB[BUF]: 16 KB, 4 x global_load_lds(16B) per thread.
#define STAGE(BUF, KC)                                                        \
  {                                                                           \
    _Pragma("unroll")                                                         \
    for (int i_ = 0; i_ < 4; ++i_) {                                          \
      int c_ = i_ * 256 + tid;                                                \
      int n_ = c_ >> 2, ko_ = (c_ & 3) * 8;                                   \
      gload_lds16(wt + n_ * 256 + (KC) * 32 + ko_, &lsB[BUF][c_ * 8]);        \
    }                                                                         \
  }

// One pipelined K-step: optional stage(K+1), optional A(K+2) issue, counted
// vmcnt, raw barriers, cvt A(K) + 16 MFMAs from lsB[K&1].
#define ITER(KC, VM, SCA, SCB, SLA, SLB, DOSTAGE, DOLOAD)                     \
  {                                                                           \
    if (DOSTAGE) STAGE(((KC) + 1) & 1, (KC) + 1);                             \
    if (DOLOAD) {                                                             \
      SLA = *(const f4*)(xrow + ((KC) + 2) * 32);                             \
      SLB = *(const f4*)(xrow + ((KC) + 2) * 32 + 4);                         \
    }                                                                         \
    WAITV(VM);                                                                \
    asm volatile("s_waitcnt lgkmcnt(0)" ::: "memory");                        \
    __builtin_amdgcn_sched_barrier(0);                                        \
    __builtin_amdgcn_s_barrier();                                             \
    FENCE();                                                                  \
    short8 fr_;                                                               \
    fr_[0]=f2bf(SCA[0]); fr_[1]=f2bf(SCA[1]); fr_[2]=f2bf(SCA[2]); fr_[3]=f2bf(SCA[3]); \
    fr_[4]=f2bf(SCB[0]); fr_[5]=f2bf(SCB[1]); fr_[6]=f2bf(SCB[2]); fr_[7]=f2bf(SCB[3]); \
    _Pragma("unroll")                                                         \
    for (int nf_ = 0; nf_ < 16; ++nf_) {                                      \
      short8 bfr_ = *(const short8*)&lsB[(KC) & 1][(nf_ * 16 + cl) * 32 + gr * 8]; \
      acc[nf_] = __builtin_amdgcn_mfma_f32_16x16x32_bf16(fr_, bfr_, acc[nf_], 0, 0, 0); \
    }                                                                         \
    FENCE();                                                                  \
    __builtin_amdgcn_s_barrier();                                             \
    FENCE();                                                                  \
  }

// Kernel 1: fused GEMM(x@W)+tanh+dot(u) -> scores; per-block softmax partials
// (m, l) and context partial. grid NBLK, 256 thr (4 waves, 16 rows each).
// B double-buffered in LDS with counted-vmcnt pipeline (never drains to 0
// mid-loop); A 2-step-ahead register prefetch in named slots.
__global__ __launch_bounds__(256, 3)
void k_scores(const float* __restrict__ x, const short* __restrict__ wt,
              const float* __restrict__ bias, const float* __restrict__ u,
              float* __restrict__ ws_scores, float* __restrict__ ws_m,
              float* __restrict__ ws_l, float* __restrict__ ws_c) {
  __shared__ __align__(16) short lsB[2][D_ * BK];   // 2 x 16 KB, linear (64B rows)
  __shared__ __align__(8) float bu[D_ * 2];         // (bias, u) pairs
  __shared__ float score_lds[BM];
  __shared__ float e_lds[BM];
  __shared__ float red_lds[1];

  const int tid  = threadIdx.x;
  const int bid  = blockIdx.x;
  const int m0   = bid * BM;
  const int lane = tid & 63;
  const int wv   = tid >> 6;       // 0..3 : 16-row group
  const int cl   = lane & 15;
  const int gr   = lane >> 4;      // 0..3

  // (bias,u) first: compiler drains their loads before the ds_write, keeping
  // the vmcnt queue empty when the pipelined loads start.
  bu[tid * 2]     = bias[tid];
  bu[tid * 2 + 1] = u[tid];

  f32x4 acc[16];
#pragma unroll
  for (int j = 0; j < 16; ++j) acc[j] = (f32x4){0.f, 0.f, 0.f, 0.f};

  const float* xrow = x + (size_t)(m0 + wv * 16 + cl) * D_ + gr * 8;

  // Prologue: queue = A(0)[2], stage(0)[4], A(1)[2]
  f4 s0a, s0b, s1a, s1b, s2a, s2b;
  s0a = *(const f4*)(xrow);       s0b = *(const f4*)(xrow + 4);
  STAGE(0, 0);
  s1a = *(const f4*)(xrow + 32);  s1b = *(const f4*)(xrow + 36);

  // Steady state: 8 outstanding (4 stage + 2+2 A) stay in flight across waits.
  ITER(0, 8, s0a, s0b, s2a, s2b, 1, 1)
  ITER(1, 8, s1a, s1b, s0a, s0b, 1, 1)
  ITER(2, 8, s2a, s2b, s1a, s1b, 1, 1)
  ITER(3, 8, s0a, s0b, s2a, s2b, 1, 1)
  ITER(4, 8, s1a, s1b, s0a, s0b, 1, 1)
  ITER(5, 8, s2a, s2b, s1a, s1b, 1, 1)
  ITER(6, 6, s0a, s0b, s0a, s0b, 1, 0)
  ITER(7, 0, s1a, s1b, s0a, s0b, 0, 0)

  // Epilogue: score[row] = sum_n tanh(acc[row][n] + b[n]) * u[n]
  float p0 = 0.f, p1 = 0.f, p2 = 0.f, p3 = 0.f;
#pragma unroll
  for (int nf = 0; nf < 16; ++nf) {
    float bb = bu[(nf * 16 + cl) * 2];
    float uu = bu[(nf * 16 + cl) * 2 + 1];
    p0 += fast_tanh(acc[nf][0] + bb) * uu;
    p1 += fast_tanh(acc[nf][1] + bb) * uu;
    p2 += fast_tanh(acc[nf][2] + bb) * uu;
    p3 += fast_tanh(acc[nf][3] + bb) * uu;
  }
#pragma unroll
  for (int m = 1; m < 16; m <<= 1) {
    p0 += __shfl_xor(p0, m);
    p1 += __shfl_xor(p1, m);
    p2 += __shfl_xor(p2, m);
    p3 += __shfl_xor(p3, m);
  }
  if (cl == 0) {
    int r = wv * 16 + gr * 4;
    score_lds[r + 0] = p0;
    score_lds[r + 1] = p1;
    score_lds[r + 2] = p2;
    score_lds[r + 3] = p3;
    ws_scores[m0 + r + 0] = p0;
    ws_scores[m0 + r + 1] = p1;
    ws_scores[m0 + r + 2] = p2;
    ws_scores[m0 + r + 3] = p3;
  }
  __syncthreads();
  // block max over 64 scores (wave 0)
  if (tid < 64) {
    float v = score_lds[tid];
#pragma unroll
    for (int m = 32; m >= 1; m >>= 1) v = fmaxf(v, __shfl_xor(v, m));
    if (tid == 0) red_lds[0] = v;
  }
  __syncthreads();
  float mb = red_lds[0];
  if (tid < BM) e_lds[tid] = __expf(score_lds[tid] - mb);
  __syncthreads();
  if (tid < 64) {
    float v = e_lds[tid];
#pragma unroll
    for (int m = 32; m >= 1; m >>= 1) v += __shfl_xor(v, m);
    if (tid == 0) { ws_m[bid] = mb; ws_l[bid] = v; }
  }
  // context partial: thread owns column d = tid; x tile is L1/L2-hot
  float cacc = 0.f;
  const float* xp = x + (size_t)m0 * D_ + tid;
#pragma unroll 4
  for (int s = 0; s < BM; ++s) cacc += e_lds[s] * xp[(size_t)s * D_];
  ws_c[bid * D_ + tid] = cacc;
}

// Kernel 2: per-batch combine of 64 block partials -> context out + (M, L)
__global__ void k_combine(const float* __restrict__ ws_m, const float* __restrict__ ws_l,
                          const float* __restrict__ ws_c, float* __restrict__ out_ctx,
                          float* __restrict__ ws_M, float* __restrict__ ws_L) {
  int b = blockIdx.x, d = threadIdx.x;
  float M = -3.4e38f;
#pragma unroll
  for (int i = 0; i < BLKS_PER_B; ++i) M = fmaxf(M, ws_m[b * BLKS_PER_B + i]);
  float L = 0.f, c = 0.f;
#pragma unroll 4
  for (int i = 0; i < BLKS_PER_B; ++i) {
    float f = __expf(ws_m[b * BLKS_PER_B + i] - M);
    L += ws_l[b * BLKS_PER_B + i] * f;
    c += ws_c[(size_t)(b * BLKS_PER_B + i) * D_ + d] * f;
  }
  out_ctx[b * D_ + d] = c / L;
  if (d == 0) { ws_M[b] = M; ws_L[b] = L; }
}

// Kernel 3: weights[b,s] = exp(score - M_b) / L_b
__global__ void k_weights(const float* __restrict__ ws_scores, const float* __restrict__ ws_M,
                          const float* __restrict__ ws_L, float* __restrict__ out_w) {
  int idx = blockIdx.x * 256 + threadIdx.x;
  int b = idx >> 12;
  out_w[idx] = __expf(ws_scores[idx] - ws_M[b]) / ws_L[b];
}

extern "C" void kernel_launch(void* const* d_in, const int* in_sizes, int n_in,
                              void* d_out, int out_size, void* d_ws, size_t ws_size,
                              hipStream_t stream) {
  (void)in_sizes; (void)n_in; (void)out_size; (void)ws_size;
  const float* x    = (const float*)d_in[0];
  const float* W    = (const float*)d_in[1];
  const float* bias = (const float*)d_in[2];
  const float* u    = (const float*)d_in[3];
  float* out_ctx = (float*)d_out;                 // [64,256]
  float* out_w   = (float*)d_out + B_ * D_;       // [64,4096]

  char* ws = (char*)d_ws;
  short* wt        = (short*)(ws + 0);            // 131072 B
  float* ws_scores = (float*)(ws + 131072);       // 1048576 B
  float* ws_m      = (float*)(ws + 1179648);      // 16384 B
  float* ws_l      = (float*)(ws + 1196032);      // 16384 B
  float* ws_c      = (float*)(ws + 1212416);      // 4194304 B
  float* ws_M      = (float*)(ws + 5406720);      // 256 B
  float* ws_L      = (float*)(ws + 5406976);      // 256 B

  hipLaunchKernelGGL(k_pack, dim3(16), dim3(1024), 0, stream, W, wt);
  hipLaunchKernelGGL(k_scores, dim3(NBLK), dim3(256), 0, stream,
                     x, wt, bias, u, ws_scores, ws_m, ws_l, ws_c);
  hipLaunchKernelGGL(k_combine, dim3(B_), dim3(256), 0, stream,
                     ws_m, ws_l, ws_c, out_ctx, ws_M, ws_L);
  hipLaunchKernelGGL(k_weights, dim3(B_ * S_ / 256), dim3(256), 0, stream,
                     ws_scores, ws_M, ws_L, out_w);
}